// Round 1
// baseline (2328.346 us; speedup 1.0000x reference)
//
#include <hip/hip_runtime.h>
#include <math.h>

// ---------------- problem constants ----------------
#define NROWS   16384      // batch N
#define INF     4096
#define OUTF    4096
#define RANK    409
#define RANK_P  512        // padded rank (zeros beyond 409)
#define NB      683        // ceil(4096/6) blocks per dim
#define NBLK2   (683*683)  // 466489
#define TOPK    46649      // ceil(466489*0.1)

typedef unsigned short u16;
typedef unsigned int   u32;
typedef unsigned long long u64;

typedef __bf16 v8bf __attribute__((ext_vector_type(8)));
typedef float  v4f  __attribute__((ext_vector_type(4)));

struct SelState { u64 prefix; u64 T; u32 kremain; };

// RNE float -> bf16 (finite inputs)
static __device__ __forceinline__ u16 f2bf(float f) {
    u32 u = __float_as_uint(f);
    u = (u + 0x7FFFu + ((u >> 16) & 1u)) >> 16;
    return (u16)u;
}

static __device__ __forceinline__ void gld_lds16(const void* g, void* l) {
    __builtin_amdgcn_global_load_lds((const __attribute__((address_space(1))) void*)g,
                                     (__attribute__((address_space(3))) void*)l,
                                     16, 0, 0);
}

// ---------------- mask pipeline ----------------

// One workgroup per bo (output-block column). Reads the 6 weight rows fully
// (coalesced), builds per-in-column |w| sums in fp64 LDS, then reduces 6-wide
// groups into pooled block means. pooled index: bo*683 + bi.
__global__ __launch_bounds__(256) void pooled_kernel(const float* __restrict__ W,
                                                     double* __restrict__ pooled) {
    __shared__ double colsum[INF];
    int bo = blockIdx.x;
    int o0 = bo * 6;
    int cc = min(6, OUTF - o0);
    int tid = threadIdx.x;
    for (int j = tid; j < INF; j += 256) {
        double s = 0.0;
        for (int d = 0; d < cc; d++)
            s += fabs((double)W[(size_t)(o0 + d) * INF + j]);
        colsum[j] = s;
    }
    __syncthreads();
    for (int bi = tid; bi < NB; bi += 256) {
        int i0 = bi * 6;
        int rc = min(6, INF - i0);
        double s = 0.0;
        for (int d = 0; d < rc; d++) s += colsum[i0 + d];
        pooled[(size_t)bo * NB + bi] = s / (double)(rc * cc);
    }
}

__global__ void init_select(u32* hist, SelState* st) {
    int t = blockIdx.x * 256 + threadIdx.x;
    if (t < 2048) hist[t] = 0;
    if (t == 0) { st->prefix = 0ull; st->T = 0ull; st->kremain = TOPK; }
}

// Radix-select histogram pass over the 64-bit patterns of the (positive)
// pooled doubles; uint64 compare == double compare for positives.
__global__ __launch_bounds__(256) void hist_kernel(const double* __restrict__ pooled,
                                                   u32* __restrict__ hist,
                                                   const SelState* __restrict__ st,
                                                   int shift, int hs, int nbins, int pass) {
    __shared__ u32 h[2048];
    int tid = threadIdx.x;
    for (int i = tid; i < nbins; i += 256) h[i] = 0;
    __syncthreads();
    int idx = blockIdx.x * 256 + tid;
    if (idx < NBLK2) {
        u64 bits = (u64)__double_as_longlong(pooled[idx]);
        bool ok = (pass == 0) || ((bits >> hs) == st->prefix);
        if (ok) atomicAdd(&h[(u32)((bits >> shift) & (u64)(nbins - 1))], 1u);
    }
    __syncthreads();
    for (int i = tid; i < nbins; i += 256)
        if (h[i]) atomicAdd(&hist[i], h[i]);
}

__global__ __launch_bounds__(256) void scan_kernel(u32* __restrict__ hist,
                                                   SelState* __restrict__ st,
                                                   int nbins, int width, int is_last) {
    __shared__ u32 h[2048];
    int tid = threadIdx.x;
    for (int i = tid; i < nbins; i += 256) h[i] = hist[i];
    __syncthreads();
    if (tid == 0) {
        u64 kr = st->kremain;
        u64 accum = 0; int chosen = 0; u64 newk = kr;
        for (int d = nbins - 1; d >= 0; d--) {
            u64 c = h[d];
            if (accum + c >= kr) { chosen = d; newk = kr - accum; break; }
            accum += c;
        }
        st->prefix = (st->prefix << width) | (u64)chosen;
        st->kremain = (u32)newk;
        if (is_last) st->T = st->prefix;
    }
    __syncthreads();
    for (int i = tid; i < nbins; i += 256) hist[i] = 0;   // ready for next pass
}

// Masked weight -> bf16, row-major (o, i). flag = pooled(bi,bo) >= T
__global__ __launch_bounds__(256) void build_wmb(const float* __restrict__ W,
                                                 const double* __restrict__ pooled,
                                                 const SelState* __restrict__ st,
                                                 u16* __restrict__ wmb) {
    size_t idx = ((size_t)blockIdx.x * 256 + threadIdx.x) * 4;
    int o = (int)(idx >> 12);
    int i = (int)(idx & 4095);
    float4 w = *(const float4*)(W + idx);
    u64 T = st->T;
    int bo = o / 6;
    float wv[4] = {w.x, w.y, w.z, w.w};
    u16 rr[4];
#pragma unroll
    for (int e = 0; e < 4; e++) {
        int bi = (i + e) / 6;
        u64 b = (u64)__double_as_longlong(pooled[(size_t)bo * NB + bi]);
        rr[e] = (b >= T) ? f2bf(wv[e]) : (u16)0;
    }
    ushort4 r; r.x = rr[0]; r.y = rr[1]; r.z = rr[2]; r.w = rr[3];
    *(ushort4*)(wmb + idx) = r;
}

// ---------------- gate + x->bf16 (fused) ----------------
__global__ __launch_bounds__(256) void gate_xb(const float* __restrict__ X,
                                               const float* __restrict__ gw,
                                               const float* __restrict__ gb,
                                               u16* __restrict__ XB,
                                               float* __restrict__ G) {
    __shared__ float red[256];
    int row = blockIdx.x, tid = threadIdx.x;
    const float* xr = X + (size_t)row * INF;
    u16* xb = XB + (size_t)row * INF;
    float dot = 0.f;
#pragma unroll
    for (int jj = 0; jj < 4; jj++) {
        int col = jj * 1024 + tid * 4;
        float4 v = *(const float4*)(xr + col);
        float4 w = *(const float4*)(gw + col);
        dot += v.x * w.x + v.y * w.y + v.z * w.z + v.w * w.w;
        ushort4 o4; o4.x = f2bf(v.x); o4.y = f2bf(v.y); o4.z = f2bf(v.z); o4.w = f2bf(v.w);
        *(ushort4*)(xb + col) = o4;
    }
    red[tid] = dot;
    __syncthreads();
    for (int s = 128; s > 0; s >>= 1) {
        if (tid < s) red[tid] += red[tid + s];
        __syncthreads();
    }
    if (tid == 0) {
        float z = red[0] + gb[0];
        G[row] = 1.f / (1.f + expf(-z));
    }
}

// ---------------- transpose+pack fp32 -> bf16, zero-pad ----------------
// dst[j][i] = (i < sr && j < sc) ? bf16(src[i][j]) : 0   for j<dr, i<dc
__global__ void transpose_pack(const float* __restrict__ src, u16* __restrict__ dst,
                               int sr, int sc, int dr, int dc) {
    __shared__ float tile[32][33];
    int i0 = blockIdx.x * 32;   // src row base / dst col base
    int j0 = blockIdx.y * 32;   // src col base / dst row base
    for (int yy = threadIdx.y; yy < 32; yy += 8) {
        int si = i0 + yy, sj = j0 + threadIdx.x;
        tile[yy][threadIdx.x] = (si < sr && sj < sc) ? src[(size_t)si * sc + sj] : 0.f;
    }
    __syncthreads();
    for (int yy = threadIdx.y; yy < 32; yy += 8) {
        int dj = j0 + yy, di = i0 + threadIdx.x;
        if (dj < dr && di < dc) dst[(size_t)dj * dc + di] = f2bf(tile[threadIdx.x][yy]);
    }
}

// ---------------- NT bf16 MFMA GEMM (m97 structure) ----------------
// C[M,N] = A[M,K] (row-major) * B[N,K] (row-major).  128x128 tile, BK=32,
// 4 waves in 2x2, each wave 4x4 frags of 16x16x32 MFMA. global_load_lds x16.
// EPI 0: store bf16 to TOUT (ldc=N)        [t = x @ lr1t]
// EPI 1: store fp32 to OUT                 [low staged in d_out]
// EPI 2: OUT = g*(acc+SB) + (1-g)*(OUT+LB) [final combine]
template <int EPI>
__global__ __launch_bounds__(256) void gemm_nt(const u16* __restrict__ A,
                                               const u16* __restrict__ B,
                                               int K, int N,
                                               float* __restrict__ OUT,
                                               u16* __restrict__ TOUT,
                                               const float* __restrict__ G,
                                               const float* __restrict__ SB,
                                               const float* __restrict__ LB) {
    __shared__ __align__(16) u16 As[128 * 32];
    __shared__ __align__(16) u16 Bs[128 * 32];
    int tid  = threadIdx.x;
    int wave = tid >> 6, lane = tid & 63;
    int quad = lane >> 4, lrow = lane & 15;
    int wm = wave >> 1, wn = wave & 1;
    int m0 = blockIdx.y * 128, n0 = blockIdx.x * 128;

    v4f acc[4][4];
#pragma unroll
    for (int i = 0; i < 4; i++)
#pragma unroll
        for (int j = 0; j < 4; j++) acc[i][j] = (v4f)0.f;

    const u16* Ab = A + (size_t)m0 * K;
    const u16* Bb = B + (size_t)n0 * K;
    int c0 = tid, c1 = tid + 256;
    int rA0 = c0 >> 2, e0 = (c0 & 3) * 8;   // row, element offset of 16B chunk
    int rA1 = c1 >> 2, e1 = (c1 & 3) * 8;
    u32 ldsOff0 = (u32)(wave * 64) * 16u;          // wave-uniform LDS byte base
    u32 ldsOff1 = (u32)(wave * 64 + 256) * 16u;

    for (int k0 = 0; k0 < K; k0 += 32) {
        __syncthreads();
        gld_lds16(Ab + (size_t)rA0 * K + k0 + e0, (char*)As + ldsOff0);
        gld_lds16(Ab + (size_t)rA1 * K + k0 + e1, (char*)As + ldsOff1);
        gld_lds16(Bb + (size_t)rA0 * K + k0 + e0, (char*)Bs + ldsOff0);
        gld_lds16(Bb + (size_t)rA1 * K + k0 + e1, (char*)Bs + ldsOff1);
        __syncthreads();

        v8bf af[4], bfv[4];
#pragma unroll
        for (int i = 0; i < 4; i++)
            af[i] = *(const v8bf*)(As + (wm * 64 + i * 16 + lrow) * 32 + quad * 8);
#pragma unroll
        for (int j = 0; j < 4; j++)
            bfv[j] = *(const v8bf*)(Bs + (wn * 64 + j * 16 + lrow) * 32 + quad * 8);
#pragma unroll
        for (int i = 0; i < 4; i++)
#pragma unroll
            for (int j = 0; j < 4; j++)
                acc[i][j] = __builtin_amdgcn_mfma_f32_16x16x32_bf16(af[i], bfv[j], acc[i][j], 0, 0, 0);
    }

#pragma unroll
    for (int i = 0; i < 4; i++) {
#pragma unroll
        for (int r = 0; r < 4; r++) {
            int grow = m0 + wm * 64 + i * 16 + quad * 4 + r;
            float gv = 0.f;
            if (EPI == 2) gv = G[grow];
#pragma unroll
            for (int j = 0; j < 4; j++) {
                int gcol = n0 + wn * 64 + j * 16 + lrow;
                float v = acc[i][j][r];
                size_t idx = (size_t)grow * N + gcol;
                if (EPI == 0) {
                    TOUT[idx] = f2bf(v);
                } else if (EPI == 1) {
                    OUT[idx] = v;
                } else {
                    float low = OUT[idx];
                    OUT[idx] = gv * (v + SB[gcol]) + (1.f - gv) * (low + LB[gcol]);
                }
            }
        }
    }
}

// ---------------- launcher ----------------
extern "C" void kernel_launch(void* const* d_in, const int* in_sizes, int n_in,
                              void* d_out, int out_size, void* d_ws, size_t ws_size,
                              hipStream_t stream) {
    const float* X   = (const float*)d_in[0];   // (16384, 4096)
    const float* GW  = (const float*)d_in[1];   // (4096, 1)
    const float* GB  = (const float*)d_in[2];   // (1,)
    const float* W   = (const float*)d_in[3];   // (4096, 4096)
    const float* SBv = (const float*)d_in[4];   // (4096,)
    const float* LR1 = (const float*)d_in[5];   // (4096, 409)
    const float* LR2 = (const float*)d_in[6];   // (409, 4096)
    const float* LBv = (const float*)d_in[7];   // (4096,)
    float* OUT = (float*)d_out;

    // workspace layout (bytes)
    const size_t OFF_POOLED = 0;                                  // 466489 * 8
    const size_t OFF_HIST   = 3 * 1024 * 1024 + 768 * 1024;       // 3.75 MB mark
    const size_t OFF_STATE  = OFF_HIST + 2048 * 4;
    const size_t OFF_XB     = 4ull * 1024 * 1024;                 // 134 MB
    const size_t OFF_WMB    = OFF_XB + (size_t)NROWS * INF * 2;   // 33.5 MB
    const size_t OFF_LR1T   = OFF_WMB + (size_t)OUTF * INF * 2;   // 4 MB
    const size_t OFF_LR2T   = OFF_LR1T + (size_t)RANK_P * INF * 2;
    const size_t OFF_T      = OFF_LR2T + (size_t)OUTF * RANK_P * 2; // 16 MB
    const size_t OFF_G      = OFF_T + (size_t)NROWS * RANK_P * 2;
    const size_t NEED       = OFF_G + (size_t)NROWS * 4;
    if (ws_size < NEED) return;  // visible failure (poison retained)

    char* ws = (char*)d_ws;
    double*   pooled = (double*)(ws + OFF_POOLED);
    u32*      hist   = (u32*)(ws + OFF_HIST);
    SelState* st     = (SelState*)(ws + OFF_STATE);
    u16*      XB     = (u16*)(ws + OFF_XB);
    u16*      WMB    = (u16*)(ws + OFF_WMB);
    u16*      LR1T   = (u16*)(ws + OFF_LR1T);
    u16*      LR2T   = (u16*)(ws + OFF_LR2T);
    u16*      Tbuf   = (u16*)(ws + OFF_T);
    float*    G      = (float*)(ws + OFF_G);

    // 1) pooled block means (fp64, deterministic)
    pooled_kernel<<<NB, 256, 0, stream>>>(W, pooled);

    // 2) exact 64-bit radix select of k-th largest pooled value
    init_select<<<8, 256, 0, stream>>>(hist, st);
    const int histGrid = (NBLK2 + 255) / 256;
    // pass: shift, hs(=shift+width), nbins, width, pass_idx, is_last
    const int sh[6]   = {53, 42, 31, 20, 9, 0};
    const int wd[6]   = {11, 11, 11, 11, 11, 9};
    for (int p = 0; p < 6; p++) {
        int nb = 1 << wd[p];
        hist_kernel<<<histGrid, 256, 0, stream>>>(pooled, hist, st, sh[p], sh[p] + wd[p], nb, p);
        scan_kernel<<<1, 256, 0, stream>>>(hist, st, nb, wd[p], (p == 5) ? 1 : 0);
    }

    // 3) packs
    build_wmb<<<(OUTF * INF) / (256 * 4), 256, 0, stream>>>(W, pooled, st, WMB);
    gate_xb<<<NROWS, 256, 0, stream>>>(X, GW, GB, XB, G);
    {
        dim3 b(32, 8);
        transpose_pack<<<dim3(INF / 32, RANK_P / 32), b, 0, stream>>>(LR1, LR1T, INF, RANK, RANK_P, INF);
        transpose_pack<<<dim3(RANK_P / 32, OUTF / 32), b, 0, stream>>>(LR2, LR2T, RANK, OUTF, OUTF, RANK_P);
    }

    // 4) GEMMs
    // t = x @ lr1   (M=16384, N=512, K=4096) -> bf16
    gemm_nt<0><<<dim3(RANK_P / 128, NROWS / 128), 256, 0, stream>>>(
        XB, LR1T, INF, RANK_P, nullptr, Tbuf, nullptr, nullptr, nullptr);
    // low = t @ lr2 (M=16384, N=4096, K=512) -> fp32 staged in d_out
    gemm_nt<1><<<dim3(OUTF / 128, NROWS / 128), 256, 0, stream>>>(
        Tbuf, LR2T, RANK_P, OUTF, OUT, nullptr, nullptr, nullptr, nullptr);
    // out = g*(x@Wm^T + sb) + (1-g)*(low + lb)
    gemm_nt<2><<<dim3(OUTF / 128, NROWS / 128), 256, 0, stream>>>(
        XB, WMB, INF, OUTF, OUT, nullptr, G, SBv, LBv);
}